// Round 1
// 252.903 us; speedup vs baseline: 1.0923x; 1.0923x over previous
//
#include <hip/hip_runtime.h>
#include <stdint.h>

typedef unsigned short u16;
typedef __attribute__((ext_vector_type(8))) short bf16x8;   // 8 bf16 = 4 VGPRs (MFMA A/B frag)
typedef __attribute__((ext_vector_type(8))) unsigned short u16x8;
typedef __attribute__((ext_vector_type(4))) float f32x4;
typedef __attribute__((ext_vector_type(4))) int i32x4;

__device__ __forceinline__ u16 f2bf(float f) {
  uint32_t u = __builtin_bit_cast(uint32_t, f);
  u += 0x7fffu + ((u >> 16) & 1u);   // RNE
  return (u16)(u >> 16);
}

// async global->LDS, 16B per lane; LDS dest must be wave-uniform base (+lane*16 implicit)
#define GLD16(g, l)                                                         \
  __builtin_amdgcn_global_load_lds(                                         \
      (const __attribute__((address_space(1))) void*)(g),                   \
      (__attribute__((address_space(3))) void*)(l), 16, 0, 0)

// ---------------- elementwise prep kernels ----------------

__global__ __launch_bounds__(256) void cvt_f32_bf16(const float* __restrict__ src,
                                                    u16* __restrict__ dst, int n8) {
  int t = blockIdx.x * 256 + threadIdx.x;
  if (t >= n8) return;
  f32x4 a = ((const f32x4*)src)[2 * t];
  f32x4 b = ((const f32x4*)src)[2 * t + 1];
  u16x8 o;
  o[0] = f2bf(a[0]); o[1] = f2bf(a[1]); o[2] = f2bf(a[2]); o[3] = f2bf(a[3]);
  o[4] = f2bf(b[0]); o[5] = f2bf(b[1]); o[6] = f2bf(b[2]); o[7] = f2bf(b[3]);
  ((u16x8*)dst)[t] = o;
}

// q:[O][G][128] int32 (flat == row-major [O][I]), s/z:[O][G] -> w bf16 [O][I]
__global__ __launch_bounds__(256) void dequant_w(const int* __restrict__ q,
                                                 const float* __restrict__ s,
                                                 const float* __restrict__ z,
                                                 u16* __restrict__ w, int n8) {
  int t = blockIdx.x * 256 + threadIdx.x;
  if (t >= n8) return;
  int g = t >> 4;                 // 8 elems/thread, 128 elems/group -> 16 threads/group
  float sc = s[g];
  float zp = z[g];
  i32x4 a = ((const i32x4*)q)[2 * t];
  i32x4 b = ((const i32x4*)q)[2 * t + 1];
  u16x8 o;
  o[0] = f2bf(((float)a[0] - zp) * sc);
  o[1] = f2bf(((float)a[1] - zp) * sc);
  o[2] = f2bf(((float)a[2] - zp) * sc);
  o[3] = f2bf(((float)a[3] - zp) * sc);
  o[4] = f2bf(((float)b[0] - zp) * sc);
  o[5] = f2bf(((float)b[1] - zp) * sc);
  o[6] = f2bf(((float)b[2] - zp) * sc);
  o[7] = f2bf(((float)b[3] - zp) * sc);
  ((u16x8*)w)[t] = o;
}

__global__ __launch_bounds__(256) void bias_init(float* __restrict__ out,
                                                 const float* __restrict__ b,
                                                 int N, int n4) {
  int t = blockIdx.x * 256 + threadIdx.x;
  if (t >= n4) return;
  int idx = t * 4;
  int n = idx & (N - 1);          // N is a power of two (2048)
  *(f32x4*)(out + idx) = *(const f32x4*)(b + n);
}

// ---------------- NT GEMM: C[M,N] = A[M,K] * B[N,K]^T (+bias, relu) ----------------
// 128x128 tile, 4 waves in 2x2, each wave 64x64 via 4x4 MFMA 16x16x32 bf16, BK=32.
// 3-deep global_load_lds pipeline with counted vmcnt (stage t+3 in flight while
// computing t; vmcnt(8) steady state, never 0 in the main loop).
// LDS XOR swizzle applied both-sides (rule #21): linear LDS dest, pre-swizzled
// GLOBAL source chunk (permutation stays within each row's 64B span -> coalescing
// unchanged), swizzled ds_read offset. Read becomes 2-way (free) instead of 8-way.
template <bool RELU, bool OUT_BF16, bool ATOMIC>
__global__ __launch_bounds__(256) void gemm_bt(const u16* __restrict__ A,
                                               const u16* __restrict__ Bm,
                                               const float* __restrict__ bias,
                                               void* __restrict__ Cout,
                                               int M, int N, int K, int kChunk) {
  __shared__ u16 As[3][128 * 32];   // 3 buffers * 8KB
  __shared__ u16 Bs[3][128 * 32];
  const int tid = threadIdx.x;
  const int wave = tid >> 6;
  const int lane = tid & 63;
  const int m0 = blockIdx.y << 7;
  const int n0 = blockIdx.x << 7;
  const int kStart = blockIdx.z * kChunk;
  const int srow = lane >> 2;                 // staging: 16 rows x 4 lanes*16B
  // staging source swizzle: lane (row=l>>2, slot=l&3) fetches global chunk slot^((row>>1)&3)
  const int scol = (((lane & 3) ^ ((lane >> 3) & 3)) << 3);
  const int wm = (wave >> 1) << 6;
  const int wn = (wave & 1) << 6;
  const int quad = lane >> 4;
  const int l15 = lane & 15;
  // read swizzle: global chunk q=quad lives at LDS slot quad^((row>>1)&3); row bits -> (l15>>1)&3
  const int cs = ((quad ^ ((l15 >> 1) & 3)) << 3);

  const u16* Ab = A + (size_t)(m0 + 32 * wave + srow) * K + kStart + scol;
  const u16* Bb = Bm + (size_t)(n0 + 32 * wave + srow) * K + kStart + scol;
  const int ldsW = (32 * wave) * 32;          // u16 offset of this wave's staging region
  const size_t rowskip = (size_t)16 * K;
  const int nT = kChunk >> 5;                 // #BK=32 steps (>=3 required; 32 or 64 here)

  f32x4 acc[4][4];
#pragma unroll
  for (int i = 0; i < 4; i++)
#pragma unroll
    for (int j = 0; j < 4; j++) acc[i][j] = (f32x4){0.f, 0.f, 0.f, 0.f};

  // stage K-step t_ into buffer bi_ : exactly 4 GLD16 per wave (vmcnt counts on this)
#define STAGE(bi_, t_)                                    \
  do {                                                    \
    const int ko_ = (t_) << 5;                            \
    GLD16(Ab + ko_, &As[bi_][ldsW]);                      \
    GLD16(Ab + ko_ + rowskip, &As[bi_][ldsW + 512]);      \
    GLD16(Bb + ko_, &Bs[bi_][ldsW]);                      \
    GLD16(Bb + ko_ + rowskip, &Bs[bi_][ldsW + 512]);      \
  } while (0)

  bf16x8 af[4], bf[4];
#define LOADFRAGS(bi_)                                                        \
  do {                                                                        \
    _Pragma("unroll") for (int i = 0; i < 4; i++)                             \
        af[i] = *(const bf16x8*)&As[bi_][(wm + i * 16 + l15) * 32 + cs];      \
    _Pragma("unroll") for (int j = 0; j < 4; j++)                             \
        bf[j] = *(const bf16x8*)&Bs[bi_][(wn + j * 16 + l15) * 32 + cs];      \
  } while (0)

#define DOMFMA()                                                              \
  do {                                                                        \
    _Pragma("unroll") for (int i = 0; i < 4; i++)                             \
        _Pragma("unroll") for (int j = 0; j < 4; j++)                         \
            acc[i][j] = __builtin_amdgcn_mfma_f32_16x16x32_bf16(              \
                af[i], bf[j], acc[i][j], 0, 0, 0);                            \
  } while (0)

  // prologue: fill the 3-deep pipe (12 loads in flight)
  STAGE(0, 0);
  STAGE(1, 1);
  STAGE(2, 2);

  int bi = 0;
  for (int t = 0; t < nT - 2; ++t) {
    // outstanding = stages {t, t+1, t+2} = 12 loads; retire the oldest 4 (stage t)
    asm volatile("s_waitcnt vmcnt(8)" ::: "memory");
    __builtin_amdgcn_s_barrier();              // all waves' stage(t) visible in LDS
    LOADFRAGS(bi);
    asm volatile("s_waitcnt lgkmcnt(0)" ::: "memory");  // frags landed in regs
    __builtin_amdgcn_s_barrier();              // all waves done reading buf bi
    if (t + 3 < nT) STAGE(bi, t + 3);          // overwrite bi with tile t+3
    DOMFMA();
    bi = (bi == 2) ? 0 : bi + 1;
  }
  // t = nT-2: outstanding = {nT-2, nT-1} = 8; retire oldest 4
  asm volatile("s_waitcnt vmcnt(4)" ::: "memory");
  __builtin_amdgcn_s_barrier();
  LOADFRAGS(bi);
  DOMFMA();
  bi = (bi == 2) ? 0 : bi + 1;
  // t = nT-1: drain
  asm volatile("s_waitcnt vmcnt(0)" ::: "memory");
  __builtin_amdgcn_s_barrier();
  LOADFRAGS(bi);
  DOMFMA();

#undef STAGE
#undef LOADFRAGS
#undef DOMFMA

  // epilogue: C/D layout col=lane&15, row=quad*4+reg (verified m89/m91)
#pragma unroll
  for (int i = 0; i < 4; i++) {
#pragma unroll
    for (int j = 0; j < 4; j++) {
      const int col = n0 + wn + j * 16 + l15;
      float bv = 0.f;
      if (!ATOMIC) bv = bias[col];
#pragma unroll
      for (int r = 0; r < 4; r++) {
        const int row = m0 + wm + i * 16 + quad * 4 + r;
        float v = acc[i][j][r];
        if (ATOMIC) {
          atomicAdd((float*)Cout + (size_t)row * N + col, v);
        } else {
          v += bv;
          if (RELU) v = v > 0.f ? v : 0.f;
          if (OUT_BF16)
            ((u16*)Cout)[(size_t)row * N + col] = f2bf(v);
          else
            ((float*)Cout)[(size_t)row * N + col] = v;
        }
      }
    }
  }
}

// ---------------- launch ----------------

extern "C" void kernel_launch(void* const* d_in, const int* in_sizes, int n_in,
                              void* d_out, int out_size, void* d_ws, size_t ws_size,
                              hipStream_t stream) {
  const float* x  = (const float*)d_in[0];
  const int*   q1 = (const int*)d_in[1];
  const float* s1 = (const float*)d_in[2];
  const float* z1 = (const float*)d_in[3];
  const float* b1 = (const float*)d_in[4];
  const int*   q2 = (const int*)d_in[5];
  const float* s2 = (const float*)d_in[6];
  const float* z2 = (const float*)d_in[7];
  const float* b2 = (const float*)d_in[8];
  float* out = (float*)d_out;

  const int B = 512, D_IN = 2048, D_H = 8192, D_OUT = 2048;

  char* ws = (char*)d_ws;
  u16* xb  = (u16*)(ws);                                   //  2 MB: x bf16 [512][2048]
  u16* w1b = (u16*)(ws + (size_t)2 * 1024 * 1024);         // 32 MB: w1 bf16 [8192][2048]
  u16* hb  = (u16*)(ws + (size_t)34 * 1024 * 1024);        //  8 MB: h bf16 [512][8192]
  u16* w2b = (u16*)(ws + (size_t)42 * 1024 * 1024);        // 32 MB: w2 bf16 [2048][8192]

  // 1. x -> bf16
  cvt_f32_bf16<<<(B * D_IN / 8 + 255) / 256, 256, 0, stream>>>(x, xb, B * D_IN / 8);
  // 2. dequant weights -> bf16
  dequant_w<<<(D_H * D_IN / 8 + 255) / 256, 256, 0, stream>>>(q1, s1, z1, w1b, D_H * D_IN / 8);
  dequant_w<<<(D_OUT * D_H / 8 + 255) / 256, 256, 0, stream>>>(q2, s2, z2, w2b, D_OUT * D_H / 8);
  // 3. h = relu(x @ w1^T + b1), bf16 out (fused epilogue, no split-K)
  dim3 g1(D_H / 128, B / 128, 1);
  gemm_bt<true, true, false><<<g1, 256, 0, stream>>>(xb, w1b, b1, hb, B, D_H, D_IN, D_IN);
  // 4. out = b2 (broadcast), then split-K=8 atomic accumulate h @ w2^T (512 blocks = 2/CU)
  bias_init<<<(B * D_OUT / 4 + 255) / 256, 256, 0, stream>>>(out, b2, D_OUT, B * D_OUT / 4);
  dim3 g2(D_OUT / 128, B / 128, 8);
  gemm_bt<false, false, true><<<g2, 256, 0, stream>>>(hb, w2b, nullptr, out, B, D_OUT, D_H, D_H / 8);
}

// Round 3
// 244.196 us; speedup vs baseline: 1.1312x; 1.0357x over previous
//
#include <hip/hip_runtime.h>
#include <stdint.h>

typedef unsigned short u16;
typedef __attribute__((ext_vector_type(8))) short bf16x8;   // 8 bf16 = 4 VGPRs (MFMA A/B frag)
typedef __attribute__((ext_vector_type(8))) unsigned short u16x8;
typedef __attribute__((ext_vector_type(4))) float f32x4;
typedef __attribute__((ext_vector_type(4))) int i32x4;

__device__ __forceinline__ u16 f2bf(float f) {
  uint32_t u = __builtin_bit_cast(uint32_t, f);
  u += 0x7fffu + ((u >> 16) & 1u);   // RNE
  return (u16)(u >> 16);
}

// async global->LDS, 16B per lane; LDS dest must be wave-uniform base (+lane*16 implicit)
#define GLD16(g, l)                                                         \
  __builtin_amdgcn_global_load_lds(                                         \
      (const __attribute__((address_space(1))) void*)(g),                   \
      (__attribute__((address_space(3))) void*)(l), 16, 0, 0)

// ---------------- elementwise prep kernels ----------------

__global__ __launch_bounds__(256) void cvt_f32_bf16(const float* __restrict__ src,
                                                    u16* __restrict__ dst, int n8) {
  int t = blockIdx.x * 256 + threadIdx.x;
  if (t >= n8) return;
  f32x4 a = ((const f32x4*)src)[2 * t];
  f32x4 b = ((const f32x4*)src)[2 * t + 1];
  u16x8 o;
  o[0] = f2bf(a[0]); o[1] = f2bf(a[1]); o[2] = f2bf(a[2]); o[3] = f2bf(a[3]);
  o[4] = f2bf(b[0]); o[5] = f2bf(b[1]); o[6] = f2bf(b[2]); o[7] = f2bf(b[3]);
  ((u16x8*)dst)[t] = o;
}

// q:[O][G][128] int32 (flat == row-major [O][I]), s/z:[O][G] -> w bf16 [O][I]
// blockIdx.z selects tensor {0: w1, 1: w2}; both are 16.78M elements here.
__global__ __launch_bounds__(256) void dequant_w2x(const int* __restrict__ qa,
                                                   const float* __restrict__ sa,
                                                   const float* __restrict__ za,
                                                   u16* __restrict__ wa,
                                                   const int* __restrict__ qb,
                                                   const float* __restrict__ sb,
                                                   const float* __restrict__ zb,
                                                   u16* __restrict__ wb, int n8) {
  int t = blockIdx.x * 256 + threadIdx.x;
  if (t >= n8) return;
  const int* q = blockIdx.z ? qb : qa;
  const float* s = blockIdx.z ? sb : sa;
  const float* z = blockIdx.z ? zb : za;
  u16* w = blockIdx.z ? wb : wa;
  int g = t >> 4;                 // 8 elems/thread, 128 elems/group -> 16 threads/group
  float sc = s[g];
  float zp = z[g];
  i32x4 a = ((const i32x4*)q)[2 * t];
  i32x4 b = ((const i32x4*)q)[2 * t + 1];
  u16x8 o;
  o[0] = f2bf(((float)a[0] - zp) * sc);
  o[1] = f2bf(((float)a[1] - zp) * sc);
  o[2] = f2bf(((float)a[2] - zp) * sc);
  o[3] = f2bf(((float)a[3] - zp) * sc);
  o[4] = f2bf(((float)b[0] - zp) * sc);
  o[5] = f2bf(((float)b[1] - zp) * sc);
  o[6] = f2bf(((float)b[2] - zp) * sc);
  o[7] = f2bf(((float)b[3] - zp) * sc);
  ((u16x8*)w)[t] = o;
}

__global__ __launch_bounds__(256) void bias_init(float* __restrict__ out,
                                                 const float* __restrict__ b,
                                                 int N, int n4) {
  int t = blockIdx.x * 256 + threadIdx.x;
  if (t >= n4) return;
  int idx = t * 4;
  int n = idx & (N - 1);          // N is a power of two (2048)
  *(f32x4*)(out + idx) = *(const f32x4*)(b + n);
}

// ---------------- NT GEMM: C[M,N] = A[M,K] * B[N,K]^T (+bias, relu) ----------------
// 128x128 tile, 4 waves in 2x2, each wave 64x64 via 4x4 MFMA 16x16x32 bf16.
// BK=64 (2 ksubs): 32 MFMA + 16 ds_read + 8 GLD16 per wave per barrier-pair
// (2x FLOP per step vs BK=32 -> per-step overhead halves per FLOP).
// 2-deep counted-vmcnt pipeline (8 loads/stage/wave; steady state vmcnt(8)).
// LDS swizzle for 128B rows: chunk ^= (row&7) (8x16B chunks/row): ds_read_b128
// lands 2-way (free, m136) instead of 8-way. Applied both-sides (rule #21):
// linear LDS dest + pre-swizzled GLOBAL source chunk (within-row permutation,
// coalescing preserved) + swizzled read offset.
// ksub-0 MFMAs run behind ksub-1 ds_read completion via lgkmcnt(8)+sched_barrier.
template <bool RELU, bool OUT_BF16, bool ATOMIC>
__global__ __launch_bounds__(256) void gemm_bt(const u16* __restrict__ A,
                                               const u16* __restrict__ Bm,
                                               const float* __restrict__ bias,
                                               void* __restrict__ Cout,
                                               int M, int N, int K, int kChunk) {
  __shared__ u16 As[2][128 * 64];   // 2 x 16KB
  __shared__ u16 Bs[2][128 * 64];   // 2 x 16KB  (total 64KB -> 2 blocks/CU)
  const int tid = threadIdx.x;
  const int wave = tid >> 6;
  const int lane = tid & 63;
  const int m0 = blockIdx.y << 7;
  const int n0 = blockIdx.x << 7;
  const int kStart = blockIdx.z * kChunk;
  // staging: each GLD16 covers 8 rows x 128B. lane -> (row=l>>3, ldsChunk=l&7);
  // fetch global chunk (l&7)^((l>>3)&7) so LDS(row,c) = global(row, c^(row&7)).
  const int srow = lane >> 3;
  const int schunk = (((lane & 7) ^ (srow & 7)) << 3);   // elem offset in row
  const int wm = (wave >> 1) << 6;
  const int wn = (wave & 1) << 6;
  const int quad = lane >> 4;
  const int l15 = lane & 15;
  const int x7 = lane & 7;                               // == l15 & 7 == row&7
  // read offsets: global chunk g = s*4+quad lives at LDS chunk g^(row&7)
  const int c0 = ((quad ^ x7) << 3);                     // ksub 0
  const int c1 = (((4 | quad) ^ x7) << 3);               // ksub 1

  const u16* Ab = A + (size_t)(m0 + 32 * wave + srow) * K + kStart + schunk;
  const u16* Bb = Bm + (size_t)(n0 + 32 * wave + srow) * K + kStart + schunk;
  const int ldsW = (32 * wave) * 64;          // u16 offset of wave's 32-row region
  const size_t rs8 = (size_t)8 * K;           // 8-row skip in global
  const int nT = kChunk >> 6;                 // #BK=64 steps (32 for gemm1, 16 for gemm2)

  f32x4 acc[4][4];
#pragma unroll
  for (int i = 0; i < 4; i++)
#pragma unroll
    for (int j = 0; j < 4; j++) acc[i][j] = (f32x4){0.f, 0.f, 0.f, 0.f};

  // stage K-step t_ into buffer bi_ : exactly 8 GLD16 per wave (vmcnt counts on this)
#define STAGE(bi_, t_)                                          \
  do {                                                          \
    const int ko_ = (t_) << 6;                                  \
    GLD16(Ab + ko_,           &As[bi_][ldsW]);                  \
    GLD16(Ab + ko_ + rs8,     &As[bi_][ldsW + 512]);            \
    GLD16(Ab + ko_ + 2 * rs8, &As[bi_][ldsW + 1024]);           \
    GLD16(Ab + ko_ + 3 * rs8, &As[bi_][ldsW + 1536]);           \
    GLD16(Bb + ko_,           &Bs[bi_][ldsW]);                  \
    GLD16(Bb + ko_ + rs8,     &Bs[bi_][ldsW + 512]);            \
    GLD16(Bb + ko_ + 2 * rs8, &Bs[bi_][ldsW + 1024]);           \
    GLD16(Bb + ko_ + 3 * rs8, &Bs[bi_][ldsW + 1536]);           \
  } while (0)

  bf16x8 af0[4], bf0[4], af1[4], bf1[4];
  // issue ksub0 reads first (8), then ksub1 (8): lgkmcnt(8) => ksub0 landed
#define LOADFRAGS(bi_)                                                          \
  do {                                                                          \
    _Pragma("unroll") for (int i = 0; i < 4; i++)                               \
        af0[i] = *(const bf16x8*)&As[bi_][(wm + i * 16 + l15) * 64 + c0];       \
    _Pragma("unroll") for (int j = 0; j < 4; j++)                               \
        bf0[j] = *(const bf16x8*)&Bs[bi_][(wn + j * 16 + l15) * 64 + c0];       \
    _Pragma("unroll") for (int i = 0; i < 4; i++)                               \
        af1[i] = *(const bf16x8*)&As[bi_][(wm + i * 16 + l15) * 64 + c1];       \
    _Pragma("unroll") for (int j = 0; j < 4; j++)                               \
        bf1[j] = *(const bf16x8*)&Bs[bi_][(wn + j * 16 + l15) * 64 + c1];       \
  } while (0)

#define MFMA_S0()                                                               \
  do {                                                                          \
    _Pragma("unroll") for (int i = 0; i < 4; i++)                               \
        _Pragma("unroll") for (int j = 0; j < 4; j++)                           \
            acc[i][j] = __builtin_amdgcn_mfma_f32_16x16x32_bf16(                \
                af0[i], bf0[j], acc[i][j], 0, 0, 0);                            \
  } while (0)

#define MFMA_S1()                                                               \
  do {                                                                          \
    _Pragma("unroll") for (int i = 0; i < 4; i++)                               \
        _Pragma("unroll") for (int j = 0; j < 4; j++)                           \
            acc[i][j] = __builtin_amdgcn_mfma_f32_16x16x32_bf16(                \
                af1[i], bf1[j], acc[i][j], 0, 0, 0);                            \
  } while (0)

  // prologue: fill the 2-deep pipe (16 loads in flight per wave)
  STAGE(0, 0);
  STAGE(1, 1);

  int bi = 0;
  // main loop: t in [0, nT-2)
  for (int t = 0; t < nT - 2; ++t) {
    // outstanding = stages {t, t+1} = 16; retire the oldest 8 (stage t)
    asm volatile("s_waitcnt vmcnt(8)" ::: "memory");
    __builtin_amdgcn_s_barrier();              // all waves' stage(t) visible in LDS
    LOADFRAGS(bi);                             // 16 ds_read_b128 issued
    asm volatile("s_waitcnt lgkmcnt(8)" ::: "memory");   // ksub0 frags landed
    __builtin_amdgcn_sched_barrier(0);         // rule #18: pin MFMA after the wait
    MFMA_S0();                                 // overlaps ksub1 read completion
    asm volatile("s_waitcnt lgkmcnt(0)" ::: "memory");   // all reads of buf bi done
    __builtin_amdgcn_sched_barrier(0);
    __builtin_amdgcn_s_barrier();              // all waves done reading buf bi
    STAGE(bi, t + 2);                          // overwrite bi with tile t+2
    MFMA_S1();                                 // overlaps stage issue / next wait
    bi ^= 1;
  }
  // t = nT-2: outstanding {nT-2, nT-1} = 16; retire oldest 8; no further staging
  asm volatile("s_waitcnt vmcnt(8)" ::: "memory");
  __builtin_amdgcn_s_barrier();
  LOADFRAGS(bi);
  asm volatile("s_waitcnt lgkmcnt(8)" ::: "memory");
  __builtin_amdgcn_sched_barrier(0);
  MFMA_S0();
  asm volatile("s_waitcnt lgkmcnt(0)" ::: "memory");
  __builtin_amdgcn_sched_barrier(0);
  MFMA_S1();
  bi ^= 1;
  // t = nT-1: drain
  asm volatile("s_waitcnt vmcnt(0)" ::: "memory");
  __builtin_amdgcn_s_barrier();
  LOADFRAGS(bi);
  asm volatile("s_waitcnt lgkmcnt(8)" ::: "memory");
  __builtin_amdgcn_sched_barrier(0);
  MFMA_S0();
  asm volatile("s_waitcnt lgkmcnt(0)" ::: "memory");
  __builtin_amdgcn_sched_barrier(0);
  MFMA_S1();

#undef STAGE
#undef LOADFRAGS
#undef MFMA_S0
#undef MFMA_S1

  // epilogue: C/D layout col=lane&15, row=quad*4+reg (verified m89/m91)
#pragma unroll
  for (int i = 0; i < 4; i++) {
#pragma unroll
    for (int j = 0; j < 4; j++) {
      const int col = n0 + wn + j * 16 + l15;
      float bv = 0.f;
      if (!ATOMIC) bv = bias[col];
#pragma unroll
      for (int r = 0; r < 4; r++) {
        const int row = m0 + wm + i * 16 + quad * 4 + r;
        float v = acc[i][j][r];
        if (ATOMIC) {
          atomicAdd((float*)Cout + (size_t)row * N + col, v);
        } else {
          v += bv;
          if (RELU) v = v > 0.f ? v : 0.f;
          if (OUT_BF16)
            ((u16*)Cout)[(size_t)row * N + col] = f2bf(v);
          else
            ((float*)Cout)[(size_t)row * N + col] = v;
        }
      }
    }
  }
}

// ---------------- launch ----------------

extern "C" void kernel_launch(void* const* d_in, const int* in_sizes, int n_in,
                              void* d_out, int out_size, void* d_ws, size_t ws_size,
                              hipStream_t stream) {
  const float* x  = (const float*)d_in[0];
  const int*   q1 = (const int*)d_in[1];
  const float* s1 = (const float*)d_in[2];
  const float* z1 = (const float*)d_in[3];
  const float* b1 = (const float*)d_in[4];
  const int*   q2 = (const int*)d_in[5];
  const float* s2 = (const float*)d_in[6];
  const float* z2 = (const float*)d_in[7];
  const float* b2 = (const float*)d_in[8];
  float* out = (float*)d_out;

  const int B = 512, D_IN = 2048, D_H = 8192, D_OUT = 2048;

  char* ws = (char*)d_ws;
  u16* xb  = (u16*)(ws);                                   //  2 MB: x bf16 [512][2048]
  u16* w1b = (u16*)(ws + (size_t)2 * 1024 * 1024);         // 32 MB: w1 bf16 [8192][2048]
  u16* hb  = (u16*)(ws + (size_t)34 * 1024 * 1024);        //  8 MB: h bf16 [512][8192]
  u16* w2b = (u16*)(ws + (size_t)42 * 1024 * 1024);        // 32 MB: w2 bf16 [2048][8192]

  // 1. x -> bf16
  cvt_f32_bf16<<<(B * D_IN / 8 + 255) / 256, 256, 0, stream>>>(x, xb, B * D_IN / 8);
  // 2. dequant both weights -> bf16 (one launch; both tensors are 16.78M elems)
  {
    const int n8 = D_H * D_IN / 8;            // == D_OUT * D_H / 8
    dim3 gd((n8 + 255) / 256, 1, 2);
    dequant_w2x<<<gd, 256, 0, stream>>>(q1, s1, z1, w1b, q2, s2, z2, w2b, n8);
  }
  // 3. h = relu(x @ w1^T + b1), bf16 out (fused epilogue, no split-K). nT = 32.
  dim3 g1(D_H / 128, B / 128, 1);
  gemm_bt<true, true, false><<<g1, 256, 0, stream>>>(xb, w1b, b1, hb, B, D_H, D_IN, D_IN);
  // 4. out = b2 (broadcast), then split-K=8 atomic accumulate h @ w2^T. nT = 16.
  bias_init<<<(B * D_OUT / 4 + 255) / 256, 256, 0, stream>>>(out, b2, D_OUT, B * D_OUT / 4);
  dim3 g2(D_OUT / 128, B / 128, 8);
  gemm_bt<false, false, true><<<g2, 256, 0, stream>>>(hb, w2b, nullptr, out, B, D_OUT, D_H, D_H / 8);
}